// Round 11
// baseline (263.777 us; speedup 1.0000x reference)
//
#include <hip/hip_runtime.h>

#define N_NODES 100000
#define N_EDGES 1000000
#define IN_DIM 32
#define HID_DIM 64
#define N2 (2 * N_NODES)          // (rel,node) buckets
#define NRANGE 8                  // dst ranges == XCD count
#define RNODES (N_NODES / NRANGE) // 12500
#define ECHUNK 2048               // edges per block-chunk in count/fill

// ============ CSR build: XCD-local histogram -> scan -> XCD-local fill ============

__global__ __launch_bounds__(256) void k_count(
    const int* __restrict__ ei, const int* __restrict__ ea,
    int* __restrict__ deg)
{
    int range = blockIdx.x & (NRANGE - 1);
    int chunk = blockIdx.x >> 3;
    int lo = range * RNODES;
    int e0 = chunk * ECHUNK;
    int e1 = min(e0 + ECHUNK, N_EDGES);
    for (int e = e0 + threadIdx.x; e < e1; e += 256) {
        int dst = ei[N_EDGES + e];
        if ((unsigned)(dst - lo) < (unsigned)RNODES) {
            int rel = ea[2 * e + 1];
            atomicAdd(&deg[rel * N_NODES + dst], 1);
        }
    }
}

__global__ __launch_bounds__(256) void k_scan_local(
    const int* __restrict__ deg, int* __restrict__ offs, int* __restrict__ bsum)
{
    int t = threadIdx.x;
    int i = blockIdx.x * 256 + t;
    int v = (i < N2) ? deg[i] : 0;
    int lane = t & 63, w = t >> 6;
    int s = v;
#pragma unroll
    for (int off = 1; off < 64; off <<= 1) {
        int u = __shfl_up(s, off);
        if (lane >= off) s += u;
    }
    __shared__ int wsum[4];
    if (lane == 63) wsum[w] = s;
    __syncthreads();
    int add = 0;
    for (int ww = 0; ww < w; ++ww) add += wsum[ww];
    s += add;
    if (i < N2) offs[i] = s - v;
    if (t == 255) bsum[blockIdx.x] = s;
}

__global__ __launch_bounds__(64) void k_scan_blocks(int* __restrict__ bsum, int nblk)
{
    int lane = threadIdx.x;  // single wave
    int carry = 0;
    for (int base = 0; base < nblk; base += 64) {
        int i = base + lane;
        int v = (i < nblk) ? bsum[i] : 0;
        int s = v;
#pragma unroll
        for (int off = 1; off < 64; off <<= 1) {
            int u = __shfl_up(s, off);
            if (lane >= off) s += u;
        }
        if (i < nblk) bsum[i] = carry + s - v;
        carry += __shfl(s, 63);
    }
}

__global__ __launch_bounds__(256) void k_scan_add(
    const int* __restrict__ offs, const int* __restrict__ bsum,
    const int* __restrict__ deg,
    int* __restrict__ cursor, int2* __restrict__ od)
{
    int i = blockIdx.x * 256 + threadIdx.x;
    if (i >= N2) return;
    int o = offs[i] + bsum[i >> 8];
    cursor[i] = o;
    od[i] = make_int2(o, deg[i]);
}

__global__ __launch_bounds__(256) void k_fill(
    const int* __restrict__ ei, const int* __restrict__ ea,
    int* __restrict__ cursor, int* __restrict__ elist)
{
    int range = blockIdx.x & (NRANGE - 1);
    int chunk = blockIdx.x >> 3;
    int lo = range * RNODES;
    int e0 = chunk * ECHUNK;
    int e1 = min(e0 + ECHUNK, N_EDGES);
    for (int e = e0 + threadIdx.x; e < e1; e += 256) {
        int dst = ei[N_EDGES + e];
        if ((unsigned)(dst - lo) < (unsigned)RNODES) {
            int rel = ea[2 * e + 1];
            int src = ei[e];
            int pos = atomicAdd(&cursor[rel * N_NODES + dst], 1);
            elist[pos] = src;
        }
    }
}

// ============ bf16 helpers ============
// r9/r10 converged at ~106 us with FETCH=131 MB vs 31 MB unique data: the
// gather's 1M x 256 B random row reads miss the per-XCD L2s (~16% hit) and
// are cache-fill-BW-bound. Fix: gather operands stored as bf16 (half bytes).
// Self paths stay exact f32; only mean terms see the 0.4% bf16 rounding.

__device__ __forceinline__ unsigned short f2bf(float f) {
    unsigned u = __float_as_uint(f);
    return (unsigned short)((u + 0x7FFFu + ((u >> 16) & 1u)) >> 16);  // RNE
}

// unpack uint2 (4 bf16: even feats in low halves) and masked-accumulate
#define BMACC4(A, u, m) {                          \
    float4 v_;                                     \
    v_.x = __uint_as_float((u).x << 16);           \
    v_.y = __uint_as_float((u).x & 0xFFFF0000u);   \
    v_.z = __uint_as_float((u).y << 16);           \
    v_.w = __uint_as_float((u).y & 0xFFFF0000u);   \
    MACC4(A, v_, m)                                \
}

__global__ __launch_bounds__(256) void k_xb(
    const float* __restrict__ x, unsigned short* __restrict__ xb)
{
    int i = blockIdx.x * 256 + threadIdx.x;       // over 800K float4s
    if (i >= N_NODES * IN_DIM / 4) return;
    float4 v = ((const float4*)x)[i];
    ushort4 o;
    o.x = f2bf(v.x); o.y = f2bf(v.y); o.z = f2bf(v.z); o.w = f2bf(v.w);
    ((ushort4*)xb)[i] = o;
}

// ============ fused layer kernels ============
// SUBGROUP-PER-NODE gather (register means, no cross-subgroup reduce) +
// v_readlane mean broadcast in the matmul (r10 structure, unchanged), with
// bf16 gather sources (r11). kk loop stays "#pragma unroll 1" (full unroll
// spills -> 3.1 GB scratch, rounds 0-2).

#define ACC4(acc, v, wa, wb, wc_, wd) \
    acc = fmaf((v).x, wa, acc);       \
    acc = fmaf((v).y, wb, acc);       \
    acc = fmaf((v).z, wc_, acc);      \
    acc = fmaf((v).w, wd, acc);

#define MACC4(A, v, m)                \
    A.x = fmaf((v).x, m, A.x);        \
    A.y = fmaf((v).y, m, A.y);        \
    A.z = fmaf((v).z, m, A.z);        \
    A.w = fmaf((v).w, m, A.w);

#define RL(v, l) __int_as_float(__builtin_amdgcn_readlane(__float_as_int(v), (l)))

#define MEANFMA(acc, Areg, ln, wa, wb, wc_, wd)   \
    acc = fmaf(RL(Areg.x, ln), wa, acc);          \
    acc = fmaf(RL(Areg.y, ln), wb, acc);          \
    acc = fmaf(RL(Areg.z, ln), wc_, acc);         \
    acc = fmaf(RL(Areg.w, ln), wd, acc);

__global__ __launch_bounds__(512, 4) void k_flayer1(
    const float* __restrict__ x,      // [N][32] f32 (self path, exact)
    const unsigned short* __restrict__ xb,  // [N][32] bf16 (gather path)
    const int2* __restrict__ od,      // [2N] (off,deg)
    const int* __restrict__ elist,    // [E]
    const float* __restrict__ root1,  // [32][64]
    const float* __restrict__ W1,     // [2][32][64]
    const float* __restrict__ b1,     // [64]
    float* __restrict__ h1,           // [N][64] f32
    unsigned short* __restrict__ h1b) // [N][64] bf16
{
    __shared__ float wR[IN_DIM * HID_DIM];
    __shared__ float w0[IN_DIM * HID_DIM];
    __shared__ float w1s[IN_DIM * HID_DIM];
    int tid = threadIdx.x;
    for (int i = tid; i < IN_DIM * HID_DIM; i += 512) {
        wR[i]  = root1[i];
        w0[i]  = W1[i];
        w1s[i] = W1[IN_DIM * HID_DIM + i];
    }

    int lane = tid & 63;
    int wv   = __builtin_amdgcn_readfirstlane(tid >> 6);
    int n0   = __builtin_amdgcn_readfirstlane(blockIdx.x * 32 + wv * 4);

    // 8 subgroups of 8 lanes: sub = r*4+i handles (node n0+i, rel r).
    int sub  = lane >> 3;
    int node = n0 + (sub & 3);
    int rel  = sub >> 2;
    int q    = lane & 7;          // feature quad 0..7 (features 4q..4q+3)
    int base = lane & 56;         // subgroup base lane

    int2 o = od[rel * N_NODES + node];
    int off = o.x, d = o.y;
    int erA = (q     < d) ? elist[off + q]     : 0;   // edges 0..7
    int erB = (8 + q < d) ? elist[off + 8 + q] : 0;   // edges 8..15

    int dm = d;
    dm = max(dm, __shfl_xor(dm, 8));
    dm = max(dm, __shfl_xor(dm, 16));
    dm = max(dm, __shfl_xor(dm, 32));           // wave max degree
    int kend = min(dm, 16);

    float4 A = make_float4(0.f, 0.f, 0.f, 0.f);
    for (int k = 0; k < kend; ++k) {
        int idx = (k < 8) ? __shfl(erA, base + k) : __shfl(erB, base + k - 8);
        uint2 u = *(const uint2*)(xb + (size_t)idx * IN_DIM + q * 4);
        float m = (k < d) ? 1.0f : 0.0f;
        BMACC4(A, u, m)
    }
    if (dm > 16) {                               // rare tail
        for (int k = 16; k < dm; ++k) {
            int idx = 0;
            if (k < d) idx = elist[off + k];
            uint2 u = *(const uint2*)(xb + (size_t)idx * IN_DIM + q * 4);
            float m = (k < d) ? 1.0f : 0.0f;
            BMACC4(A, u, m)
        }
    }
    float inv = 1.0f / fmaxf((float)d, 1.0f);
    A.x *= inv; A.y *= inv; A.z *= inv; A.w *= inv;
    // A = mean quad q of (node n0+(sub&3), rel sub>>2); readlane-addressable.

    __syncthreads();   // weight staging complete

    // ---- matmul: self rows f32 global, weights LDS, means via readlane ----
    int j = lane;
    const float* px = x + (size_t)n0 * IN_DIM;

    float accR0 = 0, accR1 = 0, accR2 = 0, accR3 = 0;
    float acc00 = 0, acc01 = 0, acc02 = 0, acc03 = 0;
    float acc10 = 0, acc11 = 0, acc12 = 0, acc13 = 0;

#pragma unroll 1
    for (int kk = 0; kk < IN_DIM / 4; ++kk) {
        int kbase = kk * 4;
        float4 xv0 = *(const float4*)(px + 0 * IN_DIM + kbase);
        float4 xv1 = *(const float4*)(px + 1 * IN_DIM + kbase);
        float4 xv2 = *(const float4*)(px + 2 * IN_DIM + kbase);
        float4 xv3 = *(const float4*)(px + 3 * IN_DIM + kbase);
        int wb_i = kbase * 64 + j;
        float wRa = wR[wb_i], wRb = wR[wb_i + 64], wRc = wR[wb_i + 128], wRd = wR[wb_i + 192];
        float w0a = w0[wb_i], w0b = w0[wb_i + 64], w0c = w0[wb_i + 128], w0d = w0[wb_i + 192];
        float w1a = w1s[wb_i], w1b = w1s[wb_i + 64], w1c = w1s[wb_i + 128], w1d = w1s[wb_i + 192];

        ACC4(accR0, xv0, wRa, wRb, wRc, wRd)
        ACC4(accR1, xv1, wRa, wRb, wRc, wRd)
        ACC4(accR2, xv2, wRa, wRb, wRc, wRd)
        ACC4(accR3, xv3, wRa, wRb, wRc, wRd)
        MEANFMA(acc00, A, 0 * 8 + kk, w0a, w0b, w0c, w0d)
        MEANFMA(acc01, A, 1 * 8 + kk, w0a, w0b, w0c, w0d)
        MEANFMA(acc02, A, 2 * 8 + kk, w0a, w0b, w0c, w0d)
        MEANFMA(acc03, A, 3 * 8 + kk, w0a, w0b, w0c, w0d)
        MEANFMA(acc10, A, 32 + 0 * 8 + kk, w1a, w1b, w1c, w1d)
        MEANFMA(acc11, A, 32 + 1 * 8 + kk, w1a, w1b, w1c, w1d)
        MEANFMA(acc12, A, 32 + 2 * 8 + kk, w1a, w1b, w1c, w1d)
        MEANFMA(acc13, A, 32 + 3 * 8 + kk, w1a, w1b, w1c, w1d)
    }

    float bj = b1[j];
    float r0 = fmaxf(accR0 + bj + acc00 + acc10, 0.0f);
    float r1 = fmaxf(accR1 + bj + acc01 + acc11, 0.0f);
    float r2 = fmaxf(accR2 + bj + acc02 + acc12, 0.0f);
    float r3 = fmaxf(accR3 + bj + acc03 + acc13, 0.0f);
    h1[(size_t)(n0 + 0) * HID_DIM + j] = r0;
    h1[(size_t)(n0 + 1) * HID_DIM + j] = r1;
    h1[(size_t)(n0 + 2) * HID_DIM + j] = r2;
    h1[(size_t)(n0 + 3) * HID_DIM + j] = r3;
    h1b[(size_t)(n0 + 0) * HID_DIM + j] = f2bf(r0);
    h1b[(size_t)(n0 + 1) * HID_DIM + j] = f2bf(r1);
    h1b[(size_t)(n0 + 2) * HID_DIM + j] = f2bf(r2);
    h1b[(size_t)(n0 + 3) * HID_DIM + j] = f2bf(r3);
}

__global__ __launch_bounds__(512, 4) void k_flayer2(
    const float* __restrict__ h1,     // [N][64] f32 (self path)
    const unsigned short* __restrict__ h1b,  // [N][64] bf16 (gather path)
    const int2* __restrict__ od,
    const int* __restrict__ elist,
    const float* __restrict__ root2,  // [64][64] -- global/L1
    const float* __restrict__ W2,     // [2][64][64]
    const float* __restrict__ b2,     // [64]
    const float* __restrict__ Wc,     // [64][2]
    const float* __restrict__ bc,     // [2]
    float* __restrict__ out)          // [N][2]
{
    __shared__ float w0[HID_DIM * HID_DIM];
    __shared__ float w1s[HID_DIM * HID_DIM];
    __shared__ float wc[HID_DIM * 2];
    int tid = threadIdx.x;
    for (int i = tid; i < HID_DIM * HID_DIM; i += 512) {
        w0[i]  = W2[i];
        w1s[i] = W2[HID_DIM * HID_DIM + i];
    }
    if (tid < HID_DIM * 2) wc[tid] = Wc[tid];

    int lane = tid & 63;
    int wv   = __builtin_amdgcn_readfirstlane(tid >> 6);
    int n0   = __builtin_amdgcn_readfirstlane(blockIdx.x * 32 + wv * 4);

    // 4 subgroups of 16 lanes: sub handles node n0+sub, both rels.
    int sub  = lane >> 4;
    int node = n0 + sub;
    int q    = lane & 15;         // feature quad 0..15
    int base = lane & 48;         // subgroup base lane

    int2 o0 = od[node];
    int2 o1 = od[N_NODES + node];
    int d0 = o0.y, d1 = o1.y;
    int er0 = (q < d0) ? elist[o0.x + q] : 0;   // edges 0..15 rel0
    int er1 = (q < d1) ? elist[o1.x + q] : 0;   // edges 0..15 rel1

    int dm = max(d0, d1);
    dm = max(dm, __shfl_xor(dm, 16));
    dm = max(dm, __shfl_xor(dm, 32));
    int kend = min(dm, 16);

    float4 A0 = make_float4(0.f, 0.f, 0.f, 0.f);
    float4 A1 = make_float4(0.f, 0.f, 0.f, 0.f);
    for (int k = 0; k < kend; ++k) {
        int i0 = __shfl(er0, base + k);
        int i1 = __shfl(er1, base + k);
        uint2 u0 = *(const uint2*)(h1b + (size_t)i0 * HID_DIM + q * 4);
        uint2 u1 = *(const uint2*)(h1b + (size_t)i1 * HID_DIM + q * 4);
        float m0 = (k < d0) ? 1.0f : 0.0f;
        float m1 = (k < d1) ? 1.0f : 0.0f;
        BMACC4(A0, u0, m0)
        BMACC4(A1, u1, m1)
    }
    if (dm > 16) {                               // rare tail
        for (int k = 16; k < dm; ++k) {
            int i0 = 0, i1 = 0;
            if (k < d0) i0 = elist[o0.x + k];
            if (k < d1) i1 = elist[o1.x + k];
            uint2 u0 = *(const uint2*)(h1b + (size_t)i0 * HID_DIM + q * 4);
            uint2 u1 = *(const uint2*)(h1b + (size_t)i1 * HID_DIM + q * 4);
            float m0 = (k < d0) ? 1.0f : 0.0f;
            float m1 = (k < d1) ? 1.0f : 0.0f;
            BMACC4(A0, u0, m0)
            BMACC4(A1, u1, m1)
        }
    }
    float i0v = 1.0f / fmaxf((float)d0, 1.0f);
    float i1v = 1.0f / fmaxf((float)d1, 1.0f);
    A0.x *= i0v; A0.y *= i0v; A0.z *= i0v; A0.w *= i0v;
    A1.x *= i1v; A1.y *= i1v; A1.z *= i1v; A1.w *= i1v;
    // A0/A1 = mean quad q of node n0+sub; quad qq at lane sub*16+qq.

    __syncthreads();   // weight staging complete

    // ---- matmul: self f32 global, w0/w1s LDS, root2 global/L1, means readlane ----
    int j = lane;
    const float* px = h1 + (size_t)n0 * HID_DIM;

    float accR0 = 0, accR1 = 0, accR2 = 0, accR3 = 0;
    float acc00 = 0, acc01 = 0, acc02 = 0, acc03 = 0;
    float acc10 = 0, acc11 = 0, acc12 = 0, acc13 = 0;

#pragma unroll 1
    for (int kk = 0; kk < HID_DIM / 4; ++kk) {
        int kbase = kk * 4;
        float4 xv0 = *(const float4*)(px + 0 * HID_DIM + kbase);
        float4 xv1 = *(const float4*)(px + 1 * HID_DIM + kbase);
        float4 xv2 = *(const float4*)(px + 2 * HID_DIM + kbase);
        float4 xv3 = *(const float4*)(px + 3 * HID_DIM + kbase);
        int wb_i = kbase * 64 + j;
        float wRa = root2[wb_i], wRb = root2[wb_i + 64];
        float wRc = root2[wb_i + 128], wRd = root2[wb_i + 192];
        float w0a = w0[wb_i], w0b = w0[wb_i + 64], w0c = w0[wb_i + 128], w0d = w0[wb_i + 192];
        float w1a = w1s[wb_i], w1b = w1s[wb_i + 64], w1c = w1s[wb_i + 128], w1d = w1s[wb_i + 192];

        ACC4(accR0, xv0, wRa, wRb, wRc, wRd)
        ACC4(accR1, xv1, wRa, wRb, wRc, wRd)
        ACC4(accR2, xv2, wRa, wRb, wRc, wRd)
        ACC4(accR3, xv3, wRa, wRb, wRc, wRd)
        MEANFMA(acc00, A0, 0 * 16 + kk, w0a, w0b, w0c, w0d)
        MEANFMA(acc01, A0, 1 * 16 + kk, w0a, w0b, w0c, w0d)
        MEANFMA(acc02, A0, 2 * 16 + kk, w0a, w0b, w0c, w0d)
        MEANFMA(acc03, A0, 3 * 16 + kk, w0a, w0b, w0c, w0d)
        MEANFMA(acc10, A1, 0 * 16 + kk, w1a, w1b, w1c, w1d)
        MEANFMA(acc11, A1, 1 * 16 + kk, w1a, w1b, w1c, w1d)
        MEANFMA(acc12, A1, 2 * 16 + kk, w1a, w1b, w1c, w1d)
        MEANFMA(acc13, A1, 3 * 16 + kk, w1a, w1b, w1c, w1d)
    }

    float bj  = b2[j];
    float wcj0 = wc[2 * j], wcj1 = wc[2 * j + 1];
    float bc0 = bc[0], bc1 = bc[1];

#define L2_OUT(i, accR, acc0, acc1)                                           \
    {                                                                         \
        int n = n0 + i;                                                       \
        float h2 = fmaxf(accR + bj + acc0 + acc1, 0.0f);                      \
        float v0 = h2 * wcj0;                                                 \
        float v1 = h2 * wcj1;                                                 \
        for (int off = 32; off >= 1; off >>= 1) {                             \
            v0 += __shfl_xor(v0, off);                                        \
            v1 += __shfl_xor(v1, off);                                        \
        }                                                                     \
        if (j == 0) {                                                         \
            out[(size_t)n * 2 + 0] = v0 + bc0;                                \
            out[(size_t)n * 2 + 1] = v1 + bc1;                                \
        }                                                                     \
    }
    L2_OUT(0, accR0, acc00, acc10)
    L2_OUT(1, accR1, acc01, acc11)
    L2_OUT(2, accR2, acc02, acc12)
    L2_OUT(3, accR3, acc03, acc13)
#undef L2_OUT
}

// ============ launch ============

extern "C" void kernel_launch(void* const* d_in, const int* in_sizes, int n_in,
                              void* d_out, int out_size, void* d_ws, size_t ws_size,
                              hipStream_t stream) {
    const float* x     = (const float*)d_in[0];
    const int*   ei    = (const int*)d_in[1];
    const int*   ea    = (const int*)d_in[2];
    const float* W1    = (const float*)d_in[3];
    const float* root1 = (const float*)d_in[4];
    const float* b1    = (const float*)d_in[5];
    const float* W2    = (const float*)d_in[6];
    const float* root2 = (const float*)d_in[7];
    const float* b2    = (const float*)d_in[8];
    const float* Wc    = (const float*)d_in[9];
    const float* bc    = (const float*)d_in[10];
    float* out = (float*)d_out;

    // ws layout (bytes), peak ~52.8 MB (proven budget >= 77.6 MB):
    //   deg    @ 0        : 2N int   (800000)
    //   offs   @ 800000   : 2N int   (800000)
    //   od     @ 1600000  : 2N int2  (1600000)
    //   elist  @ 3200000  : E int    (4000000)
    //   h1     @ 7200000  : N*64 f32 (25600000)
    //   h1b    @ 32800000 : N*64 bf16 (12800000)
    //   xb     @ 45600000 : N*32 bf16 (6400000)
    //   cursor @ 52000000 : 2N int   (800000)
    //   bsum   @ 52800000 : 1024 int
    char* ws = (char*)d_ws;
    int*   deg    = (int*)(ws);
    int*   offs   = (int*)(ws + 800000);
    int2*  od     = (int2*)(ws + 1600000);
    int*   elist  = (int*)(ws + 3200000);
    float* h1     = (float*)(ws + 7200000);
    unsigned short* h1b = (unsigned short*)(ws + 32800000);
    unsigned short* xb  = (unsigned short*)(ws + 45600000);
    int*   cursor = (int*)(ws + 52000000);
    int*   bsum   = (int*)(ws + 52800000);

    const int nblk_scan = (N2 + 255) / 256;                            // 782
    const int grid_cf   = ((N_EDGES + ECHUNK - 1) / ECHUNK) * NRANGE;  // 489*8

    hipMemsetAsync(deg, 0, (size_t)N2 * 4, stream);
    k_xb<<<(N_NODES * IN_DIM / 4 + 255) / 256, 256, 0, stream>>>(x, xb);
    k_count<<<grid_cf, 256, 0, stream>>>(ei, ea, deg);
    k_scan_local<<<nblk_scan, 256, 0, stream>>>(deg, offs, bsum);
    k_scan_blocks<<<1, 64, 0, stream>>>(bsum, nblk_scan);
    k_scan_add<<<nblk_scan, 256, 0, stream>>>(offs, bsum, deg, cursor, od);
    k_fill<<<grid_cf, 256, 0, stream>>>(ei, ea, cursor, elist);

    k_flayer1<<<N_NODES / 32, 512, 0, stream>>>(x, xb, od, elist, root1, W1, b1, h1, h1b);
    k_flayer2<<<N_NODES / 32, 512, 0, stream>>>(h1, h1b, od, elist, root2, W2, b2, Wc, bc, out);
}

// Round 12
// 230.909 us; speedup vs baseline: 1.1423x; 1.1423x over previous
//
#include <hip/hip_runtime.h>

#define N_NODES 100000
#define N_EDGES 1000000
#define IN_DIM 32
#define HID_DIM 64
#define N2 (2 * N_NODES)          // (rel,node) buckets
#define NRANGE 8                  // dst ranges == XCD count
#define RNODES (N_NODES / NRANGE) // 12500
#define ECHUNK 2048               // edges per block-chunk in count/fill

// ============ CSR build: XCD-local histogram -> scan -> XCD-local fill ============

__global__ __launch_bounds__(256) void k_count(
    const int* __restrict__ ei, const int* __restrict__ ea,
    int* __restrict__ deg)
{
    int range = blockIdx.x & (NRANGE - 1);
    int chunk = blockIdx.x >> 3;
    int lo = range * RNODES;
    int e0 = chunk * ECHUNK;
    int e1 = min(e0 + ECHUNK, N_EDGES);
    for (int e = e0 + threadIdx.x; e < e1; e += 256) {
        int dst = ei[N_EDGES + e];
        if ((unsigned)(dst - lo) < (unsigned)RNODES) {
            int rel = ea[2 * e + 1];
            atomicAdd(&deg[rel * N_NODES + dst], 1);
        }
    }
}

__global__ __launch_bounds__(256) void k_scan_local(
    const int* __restrict__ deg, int* __restrict__ offs, int* __restrict__ bsum)
{
    int t = threadIdx.x;
    int i = blockIdx.x * 256 + t;
    int v = (i < N2) ? deg[i] : 0;
    int lane = t & 63, w = t >> 6;
    int s = v;
#pragma unroll
    for (int off = 1; off < 64; off <<= 1) {
        int u = __shfl_up(s, off);
        if (lane >= off) s += u;
    }
    __shared__ int wsum[4];
    if (lane == 63) wsum[w] = s;
    __syncthreads();
    int add = 0;
    for (int ww = 0; ww < w; ++ww) add += wsum[ww];
    s += add;
    if (i < N2) offs[i] = s - v;
    if (t == 255) bsum[blockIdx.x] = s;
}

__global__ __launch_bounds__(64) void k_scan_blocks(int* __restrict__ bsum, int nblk)
{
    int lane = threadIdx.x;  // single wave
    int carry = 0;
    for (int base = 0; base < nblk; base += 64) {
        int i = base + lane;
        int v = (i < nblk) ? bsum[i] : 0;
        int s = v;
#pragma unroll
        for (int off = 1; off < 64; off <<= 1) {
            int u = __shfl_up(s, off);
            if (lane >= off) s += u;
        }
        if (i < nblk) bsum[i] = carry + s - v;
        carry += __shfl(s, 63);
    }
}

__global__ __launch_bounds__(256) void k_scan_add(
    const int* __restrict__ offs, const int* __restrict__ bsum,
    const int* __restrict__ deg,
    int* __restrict__ cursor, int2* __restrict__ od)
{
    int i = blockIdx.x * 256 + threadIdx.x;
    if (i >= N2) return;
    int o = offs[i] + bsum[i >> 8];
    cursor[i] = o;
    od[i] = make_int2(o, deg[i]);
}

__global__ __launch_bounds__(256) void k_fill(
    const int* __restrict__ ei, const int* __restrict__ ea,
    int* __restrict__ cursor, int* __restrict__ elist)
{
    int range = blockIdx.x & (NRANGE - 1);
    int chunk = blockIdx.x >> 3;
    int lo = range * RNODES;
    int e0 = chunk * ECHUNK;
    int e1 = min(e0 + ECHUNK, N_EDGES);
    for (int e = e0 + threadIdx.x; e < e1; e += 256) {
        int dst = ei[N_EDGES + e];
        if ((unsigned)(dst - lo) < (unsigned)RNODES) {
            int rel = ea[2 * e + 1];
            int src = ei[e];
            int pos = atomicAdd(&cursor[rel * N_NODES + dst], 1);
            elist[pos] = src;
        }
    }
}

// ============ helpers ============
// r11 A/B proof: halving gather FETCH (bf16) left dur unchanged at VALU 77%
// -> the broadcast matmul (512 readlane + 512 FMA/wave for means) was the
// wall. r12: LINEARITY restructure -- mean_r(x) @ W_r == mean_r(x @ W_r).
// Dense GEMM first (no gather, no readlane), then a pure gather-sum of
// pre-transformed bf16 rows. Per-node matmul eliminated.

__device__ __forceinline__ unsigned short f2bf(float f) {
    unsigned u = __float_as_uint(f);
    return (unsigned short)((u + 0x7FFFu + ((u >> 16) & 1u)) >> 16);  // RNE
}

#define ACC4(acc, v, wa, wb, wc_, wd) \
    acc = fmaf((v).x, wa, acc);       \
    acc = fmaf((v).y, wb, acc);       \
    acc = fmaf((v).z, wc_, acc);      \
    acc = fmaf((v).w, wd, acc);

#define MACC4(A, v, m)                \
    A.x = fmaf((v).x, m, A.x);        \
    A.y = fmaf((v).y, m, A.y);        \
    A.z = fmaf((v).z, m, A.z);        \
    A.w = fmaf((v).w, m, A.w);

// unpack uint2 (4 bf16) to float4
#define BUNPACK(v_, u) {                           \
    v_.x = __uint_as_float((u).x << 16);           \
    v_.y = __uint_as_float((u).x & 0xFFFF0000u);   \
    v_.z = __uint_as_float((u).y << 16);           \
    v_.w = __uint_as_float((u).y & 0xFFFF0000u);   \
}

#define BMACC4(A, u, m) { float4 v_; BUNPACK(v_, u) MACC4(A, v_, m) }

// ============ dense GEMM kernels (register-blocked, LDS weights) ============
// 512 thr = 8 waves; wave = 4 nodes; lane = output feature j. Per kk-iter:
// 4 node-row quads (wave-uniform -> scalar loads) x 3 matrices from LDS.
// Writes R = A@root + b (f32) and Y_r = A@W_r (bf16, the gather tables).
// kk loop stays "#pragma unroll 1" (full unroll spills, rounds 0-2).

__global__ __launch_bounds__(512, 4) void k_gemm1(
    const float* __restrict__ x,      // [N][32] f32
    const float* __restrict__ root1,  // [32][64]
    const float* __restrict__ W1,     // [2][32][64]
    const float* __restrict__ b1,     // [64]
    float* __restrict__ R,            // [N][64]  x@root1 + b1
    unsigned short* __restrict__ Y)   // [2][N][64] bf16: x@W1_r
{
    __shared__ float wR[IN_DIM * HID_DIM];
    __shared__ float w0[IN_DIM * HID_DIM];
    __shared__ float w1s[IN_DIM * HID_DIM];
    int tid = threadIdx.x;
    for (int i = tid; i < IN_DIM * HID_DIM; i += 512) {
        wR[i]  = root1[i];
        w0[i]  = W1[i];
        w1s[i] = W1[IN_DIM * HID_DIM + i];
    }
    __syncthreads();

    int j  = tid & 63;
    int n0 = __builtin_amdgcn_readfirstlane(blockIdx.x * 32 + ((tid >> 6) << 2));
    const float* px = x + (size_t)n0 * IN_DIM;

    float accR0 = 0, accR1 = 0, accR2 = 0, accR3 = 0;
    float acc00 = 0, acc01 = 0, acc02 = 0, acc03 = 0;
    float acc10 = 0, acc11 = 0, acc12 = 0, acc13 = 0;

#pragma unroll 1
    for (int kk = 0; kk < IN_DIM / 4; ++kk) {
        int kbase = kk * 4;
        float4 xv0 = *(const float4*)(px + 0 * IN_DIM + kbase);
        float4 xv1 = *(const float4*)(px + 1 * IN_DIM + kbase);
        float4 xv2 = *(const float4*)(px + 2 * IN_DIM + kbase);
        float4 xv3 = *(const float4*)(px + 3 * IN_DIM + kbase);
        int wb_i = kbase * 64 + j;
        float wRa = wR[wb_i], wRb = wR[wb_i + 64], wRc = wR[wb_i + 128], wRd = wR[wb_i + 192];
        float w0a = w0[wb_i], w0b = w0[wb_i + 64], w0c = w0[wb_i + 128], w0d = w0[wb_i + 192];
        float w1a = w1s[wb_i], w1b = w1s[wb_i + 64], w1c = w1s[wb_i + 128], w1d = w1s[wb_i + 192];

        ACC4(accR0, xv0, wRa, wRb, wRc, wRd)
        ACC4(accR1, xv1, wRa, wRb, wRc, wRd)
        ACC4(accR2, xv2, wRa, wRb, wRc, wRd)
        ACC4(accR3, xv3, wRa, wRb, wRc, wRd)
        ACC4(acc00, xv0, w0a, w0b, w0c, w0d)
        ACC4(acc01, xv1, w0a, w0b, w0c, w0d)
        ACC4(acc02, xv2, w0a, w0b, w0c, w0d)
        ACC4(acc03, xv3, w0a, w0b, w0c, w0d)
        ACC4(acc10, xv0, w1a, w1b, w1c, w1d)
        ACC4(acc11, xv1, w1a, w1b, w1c, w1d)
        ACC4(acc12, xv2, w1a, w1b, w1c, w1d)
        ACC4(acc13, xv3, w1a, w1b, w1c, w1d)
    }

    float bj = b1[j];
    R[(size_t)(n0 + 0) * HID_DIM + j] = accR0 + bj;
    R[(size_t)(n0 + 1) * HID_DIM + j] = accR1 + bj;
    R[(size_t)(n0 + 2) * HID_DIM + j] = accR2 + bj;
    R[(size_t)(n0 + 3) * HID_DIM + j] = accR3 + bj;
    unsigned short* Y0 = Y;
    unsigned short* Y1 = Y + (size_t)N_NODES * HID_DIM;
    Y0[(size_t)(n0 + 0) * HID_DIM + j] = f2bf(acc00);
    Y0[(size_t)(n0 + 1) * HID_DIM + j] = f2bf(acc01);
    Y0[(size_t)(n0 + 2) * HID_DIM + j] = f2bf(acc02);
    Y0[(size_t)(n0 + 3) * HID_DIM + j] = f2bf(acc03);
    Y1[(size_t)(n0 + 0) * HID_DIM + j] = f2bf(acc10);
    Y1[(size_t)(n0 + 1) * HID_DIM + j] = f2bf(acc11);
    Y1[(size_t)(n0 + 2) * HID_DIM + j] = f2bf(acc12);
    Y1[(size_t)(n0 + 3) * HID_DIM + j] = f2bf(acc13);
}

__global__ __launch_bounds__(512, 4) void k_gemm2(
    const unsigned short* __restrict__ h1b,  // [N][64] bf16
    const float* __restrict__ root2,  // [64][64]
    const float* __restrict__ W2,     // [2][64][64]
    const float* __restrict__ b2,     // [64]
    float* __restrict__ R,            // [N][64]  h1@root2 + b2
    unsigned short* __restrict__ Y)   // [2][N][64] bf16: h1@W2_r
{
    __shared__ float wR[HID_DIM * HID_DIM];
    __shared__ float w0[HID_DIM * HID_DIM];
    __shared__ float w1s[HID_DIM * HID_DIM];
    int tid = threadIdx.x;
    for (int i = tid; i < HID_DIM * HID_DIM; i += 512) {
        wR[i]  = root2[i];
        w0[i]  = W2[i];
        w1s[i] = W2[HID_DIM * HID_DIM + i];
    }
    __syncthreads();

    int j  = tid & 63;
    int n0 = __builtin_amdgcn_readfirstlane(blockIdx.x * 32 + ((tid >> 6) << 2));
    const unsigned short* pb = h1b + (size_t)n0 * HID_DIM;

    float accR0 = 0, accR1 = 0, accR2 = 0, accR3 = 0;
    float acc00 = 0, acc01 = 0, acc02 = 0, acc03 = 0;
    float acc10 = 0, acc11 = 0, acc12 = 0, acc13 = 0;

#pragma unroll 1
    for (int kk = 0; kk < HID_DIM / 4; ++kk) {
        int kbase = kk * 4;
        uint2 u0 = *(const uint2*)(pb + 0 * HID_DIM + kbase);
        uint2 u1 = *(const uint2*)(pb + 1 * HID_DIM + kbase);
        uint2 u2 = *(const uint2*)(pb + 2 * HID_DIM + kbase);
        uint2 u3 = *(const uint2*)(pb + 3 * HID_DIM + kbase);
        float4 xv0, xv1, xv2, xv3;
        BUNPACK(xv0, u0) BUNPACK(xv1, u1) BUNPACK(xv2, u2) BUNPACK(xv3, u3)
        int wb_i = kbase * 64 + j;
        float wRa = wR[wb_i], wRb = wR[wb_i + 64], wRc = wR[wb_i + 128], wRd = wR[wb_i + 192];
        float w0a = w0[wb_i], w0b = w0[wb_i + 64], w0c = w0[wb_i + 128], w0d = w0[wb_i + 192];
        float w1a = w1s[wb_i], w1b = w1s[wb_i + 64], w1c = w1s[wb_i + 128], w1d = w1s[wb_i + 192];

        ACC4(accR0, xv0, wRa, wRb, wRc, wRd)
        ACC4(accR1, xv1, wRa, wRb, wRc, wRd)
        ACC4(accR2, xv2, wRa, wRb, wRc, wRd)
        ACC4(accR3, xv3, wRa, wRb, wRc, wRd)
        ACC4(acc00, xv0, w0a, w0b, w0c, w0d)
        ACC4(acc01, xv1, w0a, w0b, w0c, w0d)
        ACC4(acc02, xv2, w0a, w0b, w0c, w0d)
        ACC4(acc03, xv3, w0a, w0b, w0c, w0d)
        ACC4(acc10, xv0, w1a, w1b, w1c, w1d)
        ACC4(acc11, xv1, w1a, w1b, w1c, w1d)
        ACC4(acc12, xv2, w1a, w1b, w1c, w1d)
        ACC4(acc13, xv3, w1a, w1b, w1c, w1d)
    }

    float bj = b2[j];
    R[(size_t)(n0 + 0) * HID_DIM + j] = accR0 + bj;
    R[(size_t)(n0 + 1) * HID_DIM + j] = accR1 + bj;
    R[(size_t)(n0 + 2) * HID_DIM + j] = accR2 + bj;
    R[(size_t)(n0 + 3) * HID_DIM + j] = accR3 + bj;
    unsigned short* Y0 = Y;
    unsigned short* Y1 = Y + (size_t)N_NODES * HID_DIM;
    Y0[(size_t)(n0 + 0) * HID_DIM + j] = f2bf(acc00);
    Y0[(size_t)(n0 + 1) * HID_DIM + j] = f2bf(acc01);
    Y0[(size_t)(n0 + 2) * HID_DIM + j] = f2bf(acc02);
    Y0[(size_t)(n0 + 3) * HID_DIM + j] = f2bf(acc03);
    Y1[(size_t)(n0 + 0) * HID_DIM + j] = f2bf(acc10);
    Y1[(size_t)(n0 + 1) * HID_DIM + j] = f2bf(acc11);
    Y1[(size_t)(n0 + 2) * HID_DIM + j] = f2bf(acc12);
    Y1[(size_t)(n0 + 3) * HID_DIM + j] = f2bf(acc13);
}

// ============ gather-sum kernels (no matmul, no LDS) ============
// 512 thr = 8 waves; wave = 4 subgroups of 16 lanes, one node each; lane
// covers feature-quad q. Sums pre-transformed Y_r rows (bf16, 128 B/row,
// one row per subgroup per wave-load), scales by 1/d, adds R, relu.

__global__ __launch_bounds__(512, 8) void k_gather1(
    const unsigned short* __restrict__ Y,  // [2][N][64] bf16
    const float* __restrict__ R,           // [N][64] (incl. b1)
    const int2* __restrict__ od,
    const int* __restrict__ elist,
    unsigned short* __restrict__ h1b)      // [N][64] bf16
{
    int tid = threadIdx.x;
    int lane = tid & 63;
    int wv   = __builtin_amdgcn_readfirstlane(tid >> 6);
    int n0   = __builtin_amdgcn_readfirstlane(blockIdx.x * 32 + wv * 4);

    int sub  = lane >> 4;
    int node = n0 + sub;
    int q    = lane & 15;
    int base = lane & 48;

    const unsigned short* Y0 = Y;
    const unsigned short* Y1 = Y + (size_t)N_NODES * HID_DIM;

    int2 o0 = od[node];
    int2 o1 = od[N_NODES + node];
    int d0 = o0.y, d1 = o1.y;
    int er0 = (q < d0) ? elist[o0.x + q] : 0;
    int er1 = (q < d1) ? elist[o1.x + q] : 0;

    int dm = max(d0, d1);
    dm = max(dm, __shfl_xor(dm, 16));
    dm = max(dm, __shfl_xor(dm, 32));
    int kend = min(dm, 16);

    float4 A0 = make_float4(0.f, 0.f, 0.f, 0.f);
    float4 A1 = make_float4(0.f, 0.f, 0.f, 0.f);
    for (int k = 0; k < kend; ++k) {
        int i0 = __shfl(er0, base + k);
        int i1 = __shfl(er1, base + k);
        uint2 u0 = *(const uint2*)(Y0 + (size_t)i0 * HID_DIM + q * 4);
        uint2 u1 = *(const uint2*)(Y1 + (size_t)i1 * HID_DIM + q * 4);
        float m0 = (k < d0) ? 1.0f : 0.0f;
        float m1 = (k < d1) ? 1.0f : 0.0f;
        BMACC4(A0, u0, m0)
        BMACC4(A1, u1, m1)
    }
    if (dm > 16) {
        for (int k = 16; k < dm; ++k) {
            int i0 = 0, i1 = 0;
            if (k < d0) i0 = elist[o0.x + k];
            if (k < d1) i1 = elist[o1.x + k];
            uint2 u0 = *(const uint2*)(Y0 + (size_t)i0 * HID_DIM + q * 4);
            uint2 u1 = *(const uint2*)(Y1 + (size_t)i1 * HID_DIM + q * 4);
            float m0 = (k < d0) ? 1.0f : 0.0f;
            float m1 = (k < d1) ? 1.0f : 0.0f;
            BMACC4(A0, u0, m0)
            BMACC4(A1, u1, m1)
        }
    }
    float i0v = 1.0f / fmaxf((float)d0, 1.0f);
    float i1v = 1.0f / fmaxf((float)d1, 1.0f);
    float4 Rq = *(const float4*)(R + (size_t)node * HID_DIM + q * 4);
    ushort4 o;
    o.x = f2bf(fmaxf(Rq.x + A0.x * i0v + A1.x * i1v, 0.0f));
    o.y = f2bf(fmaxf(Rq.y + A0.y * i0v + A1.y * i1v, 0.0f));
    o.z = f2bf(fmaxf(Rq.z + A0.z * i0v + A1.z * i1v, 0.0f));
    o.w = f2bf(fmaxf(Rq.w + A0.w * i0v + A1.w * i1v, 0.0f));
    *(ushort4*)(h1b + (size_t)node * HID_DIM + q * 4) = o;
}

__global__ __launch_bounds__(512, 8) void k_gather2(
    const unsigned short* __restrict__ Y,  // [2][N][64] bf16
    const float* __restrict__ R,           // [N][64] (incl. b2)
    const int2* __restrict__ od,
    const int* __restrict__ elist,
    const float* __restrict__ Wc,          // [64][2]
    const float* __restrict__ bc,          // [2]
    float* __restrict__ out)               // [N][2]
{
    int tid = threadIdx.x;
    int lane = tid & 63;
    int wv   = __builtin_amdgcn_readfirstlane(tid >> 6);
    int n0   = __builtin_amdgcn_readfirstlane(blockIdx.x * 32 + wv * 4);

    int sub  = lane >> 4;
    int node = n0 + sub;
    int q    = lane & 15;
    int base = lane & 48;

    const unsigned short* Y0 = Y;
    const unsigned short* Y1 = Y + (size_t)N_NODES * HID_DIM;

    int2 o0 = od[node];
    int2 o1 = od[N_NODES + node];
    int d0 = o0.y, d1 = o1.y;
    int er0 = (q < d0) ? elist[o0.x + q] : 0;
    int er1 = (q < d1) ? elist[o1.x + q] : 0;

    int dm = max(d0, d1);
    dm = max(dm, __shfl_xor(dm, 16));
    dm = max(dm, __shfl_xor(dm, 32));
    int kend = min(dm, 16);

    float4 A0 = make_float4(0.f, 0.f, 0.f, 0.f);
    float4 A1 = make_float4(0.f, 0.f, 0.f, 0.f);
    for (int k = 0; k < kend; ++k) {
        int i0 = __shfl(er0, base + k);
        int i1 = __shfl(er1, base + k);
        uint2 u0 = *(const uint2*)(Y0 + (size_t)i0 * HID_DIM + q * 4);
        uint2 u1 = *(const uint2*)(Y1 + (size_t)i1 * HID_DIM + q * 4);
        float m0 = (k < d0) ? 1.0f : 0.0f;
        float m1 = (k < d1) ? 1.0f : 0.0f;
        BMACC4(A0, u0, m0)
        BMACC4(A1, u1, m1)
    }
    if (dm > 16) {
        for (int k = 16; k < dm; ++k) {
            int i0 = 0, i1 = 0;
            if (k < d0) i0 = elist[o0.x + k];
            if (k < d1) i1 = elist[o1.x + k];
            uint2 u0 = *(const uint2*)(Y0 + (size_t)i0 * HID_DIM + q * 4);
            uint2 u1 = *(const uint2*)(Y1 + (size_t)i1 * HID_DIM + q * 4);
            float m0 = (k < d0) ? 1.0f : 0.0f;
            float m1 = (k < d1) ? 1.0f : 0.0f;
            BMACC4(A0, u0, m0)
            BMACC4(A1, u1, m1)
        }
    }
    float i0v = 1.0f / fmaxf((float)d0, 1.0f);
    float i1v = 1.0f / fmaxf((float)d1, 1.0f);
    float4 Rq = *(const float4*)(R + (size_t)node * HID_DIM + q * 4);
    float4 h2;
    h2.x = fmaxf(Rq.x + A0.x * i0v + A1.x * i1v, 0.0f);
    h2.y = fmaxf(Rq.y + A0.y * i0v + A1.y * i1v, 0.0f);
    h2.z = fmaxf(Rq.z + A0.z * i0v + A1.z * i1v, 0.0f);
    h2.w = fmaxf(Rq.w + A0.w * i0v + A1.w * i1v, 0.0f);

    // classifier: rows 4q..4q+3 of Wc[64][2]
    float4 wcA = *(const float4*)(Wc + 8 * q);      // {W[4q][0],W[4q][1],W[4q+1][0],W[4q+1][1]}
    float4 wcB = *(const float4*)(Wc + 8 * q + 4);  // {W[4q+2][0],...}
    float v0 = h2.x * wcA.x + h2.y * wcA.z + h2.z * wcB.x + h2.w * wcB.z;
    float v1 = h2.x * wcA.y + h2.y * wcA.w + h2.z * wcB.y + h2.w * wcB.w;
#pragma unroll
    for (int off = 1; off <= 8; off <<= 1) {
        v0 += __shfl_xor(v0, off);
        v1 += __shfl_xor(v1, off);
    }
    if (q == 0) {
        out[(size_t)node * 2 + 0] = v0 + bc[0];
        out[(size_t)node * 2 + 1] = v1 + bc[1];
    }
}

// ============ launch ============

extern "C" void kernel_launch(void* const* d_in, const int* in_sizes, int n_in,
                              void* d_out, int out_size, void* d_ws, size_t ws_size,
                              hipStream_t stream) {
    const float* x     = (const float*)d_in[0];
    const int*   ei    = (const int*)d_in[1];
    const int*   ea    = (const int*)d_in[2];
    const float* W1    = (const float*)d_in[3];
    const float* root1 = (const float*)d_in[4];
    const float* b1    = (const float*)d_in[5];
    const float* W2    = (const float*)d_in[6];
    const float* root2 = (const float*)d_in[7];
    const float* b2    = (const float*)d_in[8];
    const float* Wc    = (const float*)d_in[9];
    const float* bc    = (const float*)d_in[10];
    float* out = (float*)d_out;

    // ws layout (bytes), peak ~72.0 MB (proven budget >= 77.6 MB, round 0-3):
    //   deg    @ 0        : 2N int   (800000)
    //   offs   @ 800000   : 2N int   (800000)
    //   od     @ 1600000  : 2N int2  (1600000)
    //   elist  @ 3200000  : E int    (4000000)
    //   cursor @ 7200000  : 2N int   (800000)
    //   bsum   @ 8000000  : 4096
    //   Y      @ 8004096  : 2*N*64 bf16 (25600000)   reused by both layers
    //   R      @ 33604096 : N*64 f32    (25600000)   reused by both layers
    //   h1b    @ 59204096 : N*64 bf16   (12800000)
    char* ws = (char*)d_ws;
    int*   deg    = (int*)(ws);
    int*   offs   = (int*)(ws + 800000);
    int2*  od     = (int2*)(ws + 1600000);
    int*   elist  = (int*)(ws + 3200000);
    int*   cursor = (int*)(ws + 7200000);
    int*   bsum   = (int*)(ws + 8000000);
    unsigned short* Y   = (unsigned short*)(ws + 8004096);
    float* R            = (float*)(ws + 33604096);
    unsigned short* h1b = (unsigned short*)(ws + 59204096);

    const int nblk_scan = (N2 + 255) / 256;                            // 782
    const int grid_cf   = ((N_EDGES + ECHUNK - 1) / ECHUNK) * NRANGE;  // 489*8
    const int grid_n    = N_NODES / 32;                                // 3125

    hipMemsetAsync(deg, 0, (size_t)N2 * 4, stream);
    k_count<<<grid_cf, 256, 0, stream>>>(ei, ea, deg);
    k_scan_local<<<nblk_scan, 256, 0, stream>>>(deg, offs, bsum);
    k_scan_blocks<<<1, 64, 0, stream>>>(bsum, nblk_scan);
    k_scan_add<<<nblk_scan, 256, 0, stream>>>(offs, bsum, deg, cursor, od);
    k_fill<<<grid_cf, 256, 0, stream>>>(ei, ea, cursor, elist);

    // layer 1: transform-then-gather (linearity: mean(x)@W == mean(x@W))
    k_gemm1<<<grid_n, 512, 0, stream>>>(x, root1, W1, b1, R, Y);
    k_gather1<<<grid_n, 512, 0, stream>>>(Y, R, od, elist, h1b);

    // layer 2 + classifier
    k_gemm2<<<grid_n, 512, 0, stream>>>(h1b, root2, W2, b2, R, Y);
    k_gather2<<<grid_n, 512, 0, stream>>>(Y, R, od, elist, Wc, bc, out);
}